// Round 9
// baseline (140.210 us; speedup 1.0000x reference)
//
#include <hip/hip_runtime.h>

#define NT 2048
#define ND 512
#define NH 128
#define NKW 7
#define NTOK 16384

typedef float f32x4 __attribute__((ext_vector_type(4)));
typedef __bf16 bf16x8 __attribute__((ext_vector_type(8)));
typedef unsigned short u16;
typedef unsigned int u32;
typedef u16 u16x4 __attribute__((ext_vector_type(4)));
typedef u16 u16x8 __attribute__((ext_vector_type(8)));

__device__ __forceinline__ u16 f2bf(float f){
  u32 u = __builtin_bit_cast(u32, f);
  return (u16)((u + 0x7fffu + ((u>>16)&1u)) >> 16);
}
__device__ __forceinline__ float bf2f(u16 s){
  u32 u = ((u32)s)<<16;
  return __builtin_bit_cast(float, u);
}
__device__ __forceinline__ bf16x8 pack8(const float4& a, const float4& b){
  u16x8 u;
  u[0]=f2bf(a.x); u[1]=f2bf(a.y); u[2]=f2bf(a.z); u[3]=f2bf(a.w);
  u[4]=f2bf(b.x); u[5]=f2bf(b.y); u[6]=f2bf(b.z); u[7]=f2bf(b.w);
  return __builtin_bit_cast(bf16x8, u);
}
__device__ __forceinline__ void gload_lds16(const void* g, void* l){
  __builtin_amdgcn_global_load_lds(
      (const __attribute__((address_space(1))) void*)g,
      (__attribute__((address_space(3))) void*)l, 16, 0, 0);
}

// ---------------- prep2: fragment-linear weight layouts (unchanged, r6-fixed)
__global__ __launch_bounds__(256) void prep2_kernel(
    const float* __restrict__ W1, const float* __restrict__ W2,
    const float* __restrict__ b2, u16* __restrict__ W1F, u16* __restrict__ B3)
{
  int f = blockIdx.x*256 + threadIdx.x;
  u16 u[8];
  if (f < 8192){
    int n = f & 127, sk = f >> 7, kb = sk*8;
    #pragma unroll
    for (int j=0;j<8;++j) u[j] = f2bf(W1[(size_t)(kb+j)*NH + n]);
    u16x8 v;
    #pragma unroll
    for (int j=0;j<8;++j) v[j]=u[j];
    *(u16x8*)(W1F + (size_t)f*8) = v;
  } else {
    int g = f - 8192;
    int n = g & 511, sc = g >> 9, kb = sc*8;
    if (kb < 896){
      int kwin = kb >> 7, h = kb & 127;
      #pragma unroll
      for (int j=0;j<8;++j) u[j] = f2bf(W2[(size_t)(h+j)*(NKW*ND) + kwin*ND + n]);
    } else {
      int jb = kb - 896;
      #pragma unroll
      for (int j=0;j<8;++j){ int jj = jb+j; u[j] = (jj<NKW)? f2bf(b2[(size_t)jj*ND + n]) : (u16)0; }
    }
    u16x8 v;
    #pragma unroll
    for (int j=0;j<8;++j) v[j]=u[j];
    *(u16x8*)(B3 + (size_t)g*8) = v;
  }
}

// ---------------- fused2: BM=32, 256 threads (4 waves), grid 512 = 2 blocks/CU
__global__ __launch_bounds__(256,2) void fused2_kernel(
    const float* __restrict__ x, const u16* __restrict__ W1F,
    const float* __restrict__ b1, const u16* __restrict__ B3,
    const float* __restrict__ gamma, const float* __restrict__ beta,
    float* __restrict__ out)
{
  __shared__ __align__(16) u16 Bt0[16384], Bt1[16384];  // 32KB each, fragment-linear
  __shared__ __align__(16) u16 At0[1024], At1[1024];    // 2KB each, fragment-linear
  __shared__ __align__(16) u16 h_lds[32*128];           // 8KB, 256B rows, XOR swizzle
  __shared__ float rs_lds[40];
  __shared__ float s_lds[32][8];
  __shared__ float red_s[32][4], red_q[32][4];
  __shared__ float mu_lds[32], rstd_lds[32];

  const int tid = threadIdx.x, w = tid>>6, l = tid&63;
  const int m_base = blockIdx.x*32;

  // ---- P1: 38 row sums (32 rows + 6 halo), one full row per wave-iteration
  for (int t=w; t<38; t+=4){
    int g = m_base + t - 3;
    float s = 0.f;
    if (g >= 0 && g < NTOK){
      const float4* p = (const float4*)(x + (size_t)g*ND + l*8);
      float4 a = p[0], b = p[1];
      s = (a.x+a.y)+(a.z+a.w)+((b.x+b.y)+(b.z+b.w));
    }
    s += __shfl_xor(s,1); s += __shfl_xor(s,2); s += __shfl_xor(s,4);
    s += __shfl_xor(s,8); s += __shfl_xor(s,16); s += __shfl_xor(s,32);
    if (l==0) rs_lds[t] = s;
  }
  __syncthreads();
  {
    int rr = tid>>3, k = tid&7;
    float v = 0.f;
    if (k < NKW){
      int ti = (m_base+rr) & (NT-1);
      int idx = ti + k - 3;
      if (idx >= 0 && idx < NT) v = rs_lds[rr+k];
    }
    s_lds[rr][k] = v;
  }

  // ---- P2: gemm1 h = relu(x @ W1 + b1) -> h_lds (wave tile 16x64)
  {
    const int wm = w&1, wn = w>>1;
    f32x4 acc1[4] = {};
    #pragma unroll
    for (int kc=0;kc<16;++kc){
      int row = wm*16 + (l&15);
      const float4* px = (const float4*)(x + (size_t)(m_base+row)*ND + kc*32 + (l>>4)*8);
      bf16x8 af = pack8(px[0], px[1]);
      #pragma unroll
      for (int ni=0;ni<4;++ni){
        int n = wn*64 + ni*16 + (l&15);
        bf16x8 bfr = *(const bf16x8*)(W1F + ((size_t)(kc*4+(l>>4))*128 + n)*8);
        acc1[ni] = __builtin_amdgcn_mfma_f32_16x16x32_bf16(af, bfr, acc1[ni],0,0,0);
      }
    }
    #pragma unroll
    for (int ni=0;ni<4;++ni){
      int col = wn*64 + ni*16 + (l&15);
      float bias = b1[col];
      #pragma unroll
      for (int r=0;r<4;++r){
        int row = wm*16 + (l>>4)*4 + r;
        float v = fmaxf(acc1[ni][r] + bias, 0.f);
        int byte = row*256 + ((2*col) ^ ((row&7)<<4));
        *(u16*)((char*)h_lds + byte) = f2bf(v);
      }
    }
  }
  __syncthreads();

  // ---- P3: gemm2, 28 chunks of BK=32 + bias chunk, depth-1 gload_lds pipeline
  f32x4 acc[2][8] = {};
  const int srow = (tid>>1)&31, shalf = tid&1;   // staging slot = tid>>1 = (tid>>6)*32+srow
  const int s_rowbase = srow*256, s_xor = (srow&7)<<4;

  auto stageB = [&](int c, u16* dstB){
    #pragma unroll
    for (int i=0;i<8;++i){
      int seg = w*8 + i;
      const char* g = (const char*)B3 + (size_t)c*32768 + seg*1024 + l*16;
      gload_lds16(g, (char*)dstB + seg*1024);
    }
  };
  auto stageA = [&](int c, u16* dstA){   // c is compile-time after unroll
    float sv = s_lds[srow][c>>2];
    int slotbyte = (c&3)*64 + w*16;
    u16x4 hv = *(const u16x4*)((const char*)h_lds + s_rowbase + (slotbyte ^ s_xor) + shalf*8);
    u16x4 o;
    #pragma unroll
    for (int j=0;j<4;++j) o[j] = f2bf(bf2f(hv[j]) * sv);
    *(u16x4*)(dstA + tid*4) = o;
  };
  auto stageAbias = [&](u16* dstA){
    u16x4 o;
    #pragma unroll
    for (int j=0;j<4;++j){
      float v = 0.f;
      if (w==0){
        int k = shalf*4 + j;
        if (k < NKW) v = s_lds[srow][k];
      }
      o[j] = f2bf(v);
    }
    *(u16x4*)(dstA + tid*4) = o;
  };
  auto mfmaC = [&](const u16* A, const u16* B){
    int abase = ((l>>4)*32 + (l&15))*8;
    bf16x8 af0 = *(const bf16x8*)(A + abase);
    bf16x8 af1 = *(const bf16x8*)(A + abase + 16*8);
    int bbase = ((l>>4)*512 + w*128 + (l&15))*8;
    __builtin_amdgcn_s_setprio(1);
    #pragma unroll
    for (int ni=0;ni<8;++ni){
      bf16x8 bf = *(const bf16x8*)(B + bbase + ni*16*8);
      acc[0][ni] = __builtin_amdgcn_mfma_f32_16x16x32_bf16(af0, bf, acc[0][ni],0,0,0);
      acc[1][ni] = __builtin_amdgcn_mfma_f32_16x16x32_bf16(af1, bf, acc[1][ni],0,0,0);
    }
    __builtin_amdgcn_s_setprio(0);
  };

  stageB(0, Bt0);
  stageA(0, At0);
  __syncthreads();
  #pragma unroll
  for (int t=0;t<14;++t){
    stageB(2*t+1, Bt1);
    __builtin_amdgcn_sched_barrier(0);
    stageA(2*t+1, At1);
    mfmaC(At0, Bt0);
    __syncthreads();
    if (t < 13){
      stageB(2*t+2, Bt0);
      __builtin_amdgcn_sched_barrier(0);
      stageA(2*t+2, At0);
    } else {
      stageB(28, Bt0);
      __builtin_amdgcn_sched_barrier(0);
      stageAbias(At0);
    }
    mfmaC(At1, Bt1);
    __syncthreads();
  }
  mfmaC(At0, Bt0);   // bias chunk

  // ---- P4: residual + LN + relu (wave w owns cols w*128..+128)
  float gv[8], bv[8];
  #pragma unroll
  for (int ni=0;ni<8;++ni){
    int n = w*128 + ni*16 + (l&15);
    gv[ni] = gamma[n]; bv[ni] = beta[n];
  }
  #pragma unroll
  for (int mi=0;mi<2;++mi){
    #pragma unroll
    for (int r=0;r<4;++r){
      int m = mi*16 + (l>>4)*4 + r;
      int tg = m_base + m;
      float ps=0.f, pq=0.f;
      #pragma unroll
      for (int ni=0;ni<8;++ni){
        int n = w*128 + ni*16 + (l&15);
        float v = acc[mi][ni][r] + x[(size_t)tg*ND + n];
        acc[mi][ni][r] = v;
        ps += v; pq += v*v;
      }
      ps += __shfl_xor(ps,1); pq += __shfl_xor(pq,1);
      ps += __shfl_xor(ps,2); pq += __shfl_xor(pq,2);
      ps += __shfl_xor(ps,4); pq += __shfl_xor(pq,4);
      ps += __shfl_xor(ps,8); pq += __shfl_xor(pq,8);
      if ((l&15)==0){ red_s[m][w]=ps; red_q[m][w]=pq; }
    }
  }
  __syncthreads();
  if (tid < 32){
    float ssum = red_s[tid][0]+red_s[tid][1]+red_s[tid][2]+red_s[tid][3];
    float sq   = red_q[tid][0]+red_q[tid][1]+red_q[tid][2]+red_q[tid][3];
    float mu = ssum * (1.0f/ND);
    float var = sq*(1.0f/ND) - mu*mu;
    mu_lds[tid] = mu;
    rstd_lds[tid] = rsqrtf(var + 1e-3f);
  }
  __syncthreads();
  #pragma unroll
  for (int mi=0;mi<2;++mi){
    #pragma unroll
    for (int r=0;r<4;++r){
      int m = mi*16 + (l>>4)*4 + r;
      int tg = m_base + m;
      float mu = mu_lds[m], rstd = rstd_lds[m];
      #pragma unroll
      for (int ni=0;ni<8;++ni){
        int n = w*128 + ni*16 + (l&15);
        float v = (acc[mi][ni][r]-mu)*rstd*gv[ni] + bv[ni];
        out[(size_t)tg*ND + n] = fmaxf(v, 0.f);
      }
    }
  }
}

extern "C" void kernel_launch(void* const* d_in, const int* in_sizes, int n_in,
                              void* d_out, int out_size, void* d_ws, size_t ws_size,
                              hipStream_t stream)
{
  (void)in_sizes; (void)n_in; (void)out_size; (void)ws_size;
  const float* x     = (const float*)d_in[0];
  const float* W1    = (const float*)d_in[1];
  const float* b1    = (const float*)d_in[2];
  const float* W2    = (const float*)d_in[3];
  const float* b2    = (const float*)d_in[4];
  const float* gamma = (const float*)d_in[5];
  const float* beta  = (const float*)d_in[6];
  float* out = (float*)d_out;

  char* ws = (char*)d_ws;
  u16* W1F = (u16*)(ws);               // 131072 B
  u16* B3  = (u16*)(ws + 131072);      // 983040 B

  prep2_kernel<<<272, 256, 0, stream>>>(W1, W2, b2, W1F, B3);
  fused2_kernel<<<512, 256, 0, stream>>>(x, W1F, b1, B3, gamma, beta, out);
}